// Round 6
// baseline (546.564 us; speedup 1.0000x reference)
//
#include <hip/hip_runtime.h>

typedef __attribute__((ext_vector_type(8))) short short8;
typedef __attribute__((ext_vector_type(4))) float f32x4;
typedef __attribute__((ext_vector_type(8))) unsigned short ushx8;

#define E_EDGES 800000
#define TILE 64
#define NTILES (E_EDGES / TILE)   // 12500 exact

// ws layout, ushort units
#define WS_TSD 0                   // [9216][128] bf16: Tsrc[zs]+Tdst[zd]
#define WS_TSE 1179648             // [40][128]  bf16: Tstep[st]+Teq[qe]+bias
#define WS_W2T 1184768             // [n=0..127][k=0..127], W2T[n][k] = W[256+k][n]
#define WS_WRBFT 1201152           // [n=0..127][k=0..31], zero-padded past k=6
// byte offsets (tables end at 2,410,496 B)
#define WSB_META 4194304u                   // int2[E] = 6.4 MB
#define WSB_RBF8 10594304u                  // ushx8[E] = 12.8 MB

#define IDX_BLOCKS 3125
#define TSD_BLOCKS 576             // 16 Tsd rows per block -> 9216
#define TSE_BLOCKS 20              // 2 rows per block -> 40
#define TR_BLOCKS  64              // 2 rows per block -> 128

__device__ __forceinline__ unsigned short f2bf(float f) {
    unsigned int u = __float_as_uint(f);
    u += 0x7fffu + ((u >> 16) & 1u);   // RNE
    return (unsigned short)(u >> 16);
}
__device__ __forceinline__ float bf2f(unsigned short u) {
    return __uint_as_float(((unsigned int)u) << 16);
}
__device__ __forceinline__ float silu_f(float v) {
    return v * __builtin_amdgcn_rcpf(1.0f + __expf(-v));
}
// LDS-only barrier: global loads/stores stay in flight across it.
__device__ __forceinline__ void barrier_lds() {
    asm volatile("s_waitcnt lgkmcnt(0)\n\ts_barrier" ::: "memory");
}

// ---- Merged prestage: index part + table-build parts (all independent) ------
__global__ __launch_bounds__(256)
void prestage_kernel(const int* __restrict__ Z, const int* __restrict__ stepv,
                     const int* __restrict__ src, const int* __restrict__ dst,
                     const int* __restrict__ equiv, const float* __restrict__ rbf,
                     const float* __restrict__ dvec,
                     const float* __restrict__ emb, const float* __restrict__ stept,
                     const float* __restrict__ eqt, const float* __restrict__ Wrbf,
                     const float* __restrict__ W, const float* __restrict__ bias,
                     unsigned short* __restrict__ ws, unsigned char* __restrict__ wsb,
                     float* __restrict__ out) {
    const int t = threadIdx.x;
    const int bid = blockIdx.x;
    if (bid < IDX_BLOCKS) {
        // ------------- index part: meta(int2), rbf->bf16, rbf_env -------------
        __shared__ float rl[1536];
        __shared__ float el[1536];
        const int B0 = bid * 256;
        const int e = B0 + t;
        #pragma unroll
        for (int i = 0; i < 6; ++i) rl[t + i*256] = rbf[B0*6 + t + i*256];
        const int s  = src[e];
        const int dd = dst[e];
        const int qe = equiv[e];
        const float x = dvec[e] * 0.2f;
        ((int2*)(wsb + WSB_META))[e] =
            make_int2((Z[s]*96 + Z[dd])*128, (stepv[s]*2 + qe)*128);
        const float inv = __builtin_amdgcn_rcpf(x);
        const float x2 = x*x;
        const float x5 = x2*x2*x;
        const float env = inv + x5*(-28.f + x*(48.f - 21.f*x));
        #pragma unroll
        for (int rr = 0; rr < 6; ++rr)
            el[t*6 + rr] = env * __sinf(x * (3.14159265358979f * (rr + 1))) * inv;
        __syncthreads();
        ushx8 v;
        #pragma unroll
        for (int k = 0; k < 6; ++k) v[k] = f2bf(rl[t*6 + k]);
        v[6] = 0; v[7] = 0;
        *(ushx8*)(wsb + WSB_RBF8 + 16u*e) = v;
        #pragma unroll
        for (int i = 0; i < 6; ++i)
            __builtin_nontemporal_store(el[t + i*256],
                &out[(long)E_EDGES*128 + B0*6 + t + i*256]);
    } else if (bid < IDX_BLOCKS + TSD_BLOCKS) {
        // ------------- Tsd[p] = emb[zs]@W0 + emb[zd]@W1, p = zs*96+zd ---------
        const int bt = bid - IDX_BLOCKS;
        const int j  = t & 127;
        const int p0 = bt*16 + (t >> 7)*8;     // 8 rows per half-block
        int zs[8], zd[8];
        #pragma unroll
        for (int rr = 0; rr < 8; ++rr) {
            const int p = p0 + rr;
            zs[rr] = p / 96;
            zd[rr] = p - zs[rr]*96;
        }
        float acc[8] = {0.f,0.f,0.f,0.f,0.f,0.f,0.f,0.f};
        #pragma unroll 2
        for (int k = 0; k < 128; ++k) {
            const float w1 = W[k*128 + j];
            const float w2 = W[(128 + k)*128 + j];
            #pragma unroll
            for (int rr = 0; rr < 8; ++rr)
                acc[rr] += emb[zs[rr]*128 + k]*w1 + emb[zd[rr]*128 + k]*w2;
        }
        #pragma unroll
        for (int rr = 0; rr < 8; ++rr)
            ws[WS_TSD + (p0 + rr)*128 + j] = f2bf(acc[rr]);
    } else if (bid < IDX_BLOCKS + TSD_BLOCKS + TSE_BLOCKS) {
        // ------------- Tse[q8] = stept[st]@W3 + eqt[qe]@W4 + bias -------------
        const int bt = bid - IDX_BLOCKS - TSD_BLOCKS;
        const int j  = t & 127;
        const int q8 = bt*2 + (t >> 7);        // 0..39
        const int st = q8 >> 1, qe = q8 & 1;
        float acc = bias[j];
        #pragma unroll 2
        for (int k = 0; k < 128; ++k)
            acc += stept[st*128 + k]*W[(384 + k)*128 + j]
                 + eqt[qe*128 + k]*W[(512 + k)*128 + j];
        ws[WS_TSE + q8*128 + j] = f2bf(acc);
    } else {
        // ------------- W2T / WRBFT transposes ---------------------------------
        const int bt = bid - IDX_BLOCKS - TSD_BLOCKS - TSE_BLOCKS;
        const int j  = t & 127;
        const int n  = bt*2 + (t >> 7);        // 0..127
        ws[WS_W2T + n*128 + j] = f2bf(W[(256 + j)*128 + n]);
        if (j < 32)
            ws[WS_WRBFT + n*32 + j] = (j < 6) ? f2bf(Wrbf[j*128 + n]) : (unsigned short)0;
    }
}

// ---------------- Kernel M: persistent fused edge kernel ----------------------
// Pipeline: gathers for tile t+1 issued in tile t's phase-2 shadow (8 ushx8 in
// regs); phase 0 of tile t is pure reg->LDS (no global latency on the path).
__global__ __launch_bounds__(256, 3)
void edge_kernel(const unsigned short* __restrict__ ws,
                 const unsigned char* __restrict__ wsb,
                 const float* __restrict__ brbf_g, float* __restrict__ out) {
    __shared__ alignas(16) unsigned short rbf_a[TILE*136];  // 17.0 KB
    __shared__ alignas(16) float sumbuf[TILE*132];          // 33.0 KB
    __shared__ alignas(16) int2  meta_l[2][TILE];           // 1 KB (double-buffered)
    __shared__ alignas(16) int   rbf8_l[256];               // 1 KB
    // total 52 KB -> 3 blocks/CU

    const int t = threadIdx.x;
    const int lane = t & 63;
    const int w = t >> 6;
    const int q = lane >> 4;
    const int r = lane & 15;
    const int mh = w >> 1;        // edge sub-tile [mh*16, +16)
    const int nh = w & 1;         // col half [nh*64, +64)
    const int arow = mh*16 + r;

    const unsigned short* TSD = ws + WS_TSD;
    const unsigned short* TSE = ws + WS_TSE;
    const unsigned short* W2T = ws + WS_W2T;
    const unsigned short* WRB = ws + WS_WRBFT;
    const int* g_meta_i = (const int*)(wsb + WSB_META);   // 128 dwords / tile
    const int* g_rbf8_i = (const int*)(wsb + WSB_RBF8);   // 256 dwords / tile

    // block-invariant B-fragments in VGPRs
    short8 w2f[16];
    short8 wrbf[4];
    float  brbf[4];
    #pragma unroll
    for (int nt = 0; nt < 4; ++nt) {
        const int n = nh*64 + nt*16 + r;
        #pragma unroll
        for (int ks = 0; ks < 4; ++ks)
            w2f[nt*4+ks] = *(const short8*)(W2T + n*128 + ks*32 + q*8);
        wrbf[nt] = *(const short8*)(WRB + n*32 + q*8);
        brbf[nt] = brbf_g[n];
    }

    const int el8 = t >> 4;          // edge sub-index 0..15
    const int c0  = (t & 15) * 8;    // col chunk (8 ushorts = 16 B)
    const int stride = gridDim.x;

    ushx8 u0[4], u1[4];              // prefetched gather data (32 VGPRs)

    // ---- prologue: meta(T0)->slot1, meta(Tn1)->slot0, rbf8(T0); issue gathers(T0)
    const int T0 = blockIdx.x;
    {
        const int Tn1 = (T0 + stride < NTILES) ? T0 + stride : T0;
        if (t < 128) ((int*)(meta_l[1]))[t]       = g_meta_i[T0*128 + t];
        else         ((int*)(meta_l[0]))[t - 128] = g_meta_i[Tn1*128 + (t - 128)];
        rbf8_l[t] = g_rbf8_i[T0*256 + t];
        barrier_lds();
        #pragma unroll
        for (int i = 0; i < 4; ++i) {
            const int2 mo = meta_l[1][i*16 + el8];
            u0[i] = *(const ushx8*)(TSD + mo.x + c0);
            u1[i] = *(const ushx8*)(TSE + mo.y + c0);
        }
    }

    int ph = 0;
    for (int tile = T0; tile < NTILES; tile += stride) {
        const int base = tile * TILE;
        const int Tn1 = (tile +   stride < NTILES) ? tile +   stride : tile;
        const int Tn2 = (tile + 2*stride < NTILES) ? tile + 2*stride : Tn1;

        // ---- top: global prefetches (independent, land by phase-2) ----
        int mreg = 0;
        if (t < 128) mreg = g_meta_i[Tn2*128 + t];
        const int rnext = g_rbf8_i[Tn1*256 + t];

        // ---- phase 0: table sums for CURRENT tile, from prefetched regs ----
        #pragma unroll
        for (int i = 0; i < 4; ++i) {
            const int e = i*16 + el8;
            float* srow = sumbuf + e*132 + c0;
            f32x4 sv0, sv1;
            #pragma unroll
            for (int k = 0; k < 4; ++k) {
                sv0[k] = bf2f(u0[i][k])   + bf2f(u1[i][k]);
                sv1[k] = bf2f(u0[i][k+4]) + bf2f(u1[i][k+4]);
            }
            *(f32x4*)(srow)     = sv0;
            *(f32x4*)(srow + 4) = sv1;
        }

        // ---- phase 1b: mini-MFMA rbf_a = silu(rbf @ W_rbf + b) ----
        {
            short8 a0 = (short8)0;
            if (q == 0) a0 = ((const short8*)rbf8_l)[arow];
            #pragma unroll
            for (int nt = 0; nt < 4; ++nt) {
                const float bb = brbf[nt];
                f32x4 c = {bb, bb, bb, bb};
                c = __builtin_amdgcn_mfma_f32_16x16x32_bf16(a0, wrbf[nt], c, 0, 0, 0);
                const int col = nh*64 + nt*16 + r;
                #pragma unroll
                for (int reg = 0; reg < 4; ++reg)
                    rbf_a[(mh*16 + q*4 + reg)*136 + col] = f2bf(silu_f(c[reg]));
            }
        }
        barrier_lds();

        // ---- (a) issue gathers for NEXT tile (latency hides under phase 2) --
        #pragma unroll
        for (int i = 0; i < 4; ++i) {
            const int2 mo = meta_l[ph][i*16 + el8];
            u0[i] = *(const ushx8*)(TSD + mo.x + c0);
            u1[i] = *(const ushx8*)(TSE + mo.y + c0);
        }
        // ---- (b) publish next-next meta / next rbf8 ----
        if (t < 128) ((int*)(meta_l[ph ^ 1]))[t] = mreg;
        rbf8_l[t] = rnext;

        // ---- (c) phase 2: main MFMA (C init = table sums), silu, NT stores --
        f32x4 acc[4];
        #pragma unroll
        for (int nt = 0; nt < 4; ++nt) {
            const int col = nh*64 + nt*16 + r;
            #pragma unroll
            for (int reg = 0; reg < 4; ++reg)
                acc[nt][reg] = sumbuf[(mh*16 + q*4 + reg)*132 + col];
        }
        #pragma unroll
        for (int ks = 0; ks < 4; ++ks) {
            short8 a = *(const short8*)(rbf_a + arow*136 + ks*32 + q*8);
            #pragma unroll
            for (int nt = 0; nt < 4; ++nt)
                acc[nt] = __builtin_amdgcn_mfma_f32_16x16x32_bf16(a, w2f[nt*4+ks], acc[nt], 0, 0, 0);
        }
        #pragma unroll
        for (int nt = 0; nt < 4; ++nt) {
            const int col = nh*64 + nt*16 + r;
            #pragma unroll
            for (int reg = 0; reg < 4; ++reg)
                __builtin_nontemporal_store(silu_f(acc[nt][reg]),
                    &out[(long)(base + mh*16 + q*4 + reg)*128 + col]);
        }
        barrier_lds();   // protect sumbuf/rbf_a + published meta/rbf8
        ph ^= 1;
    }
}

extern "C" void kernel_launch(void* const* d_in, const int* in_sizes, int n_in,
                              void* d_out, int out_size, void* d_ws, size_t ws_size,
                              hipStream_t stream) {
    const int*   Z     = (const int*)d_in[0];
    const int*   stepv = (const int*)d_in[1];
    const int*   src   = (const int*)d_in[2];
    const int*   dst   = (const int*)d_in[3];
    const int*   equiv = (const int*)d_in[4];
    const float* rbf   = (const float*)d_in[5];
    const float* dvec  = (const float*)d_in[6];
    const float* emb   = (const float*)d_in[7];
    const float* stept = (const float*)d_in[8];
    const float* eqt   = (const float*)d_in[9];
    const float* Wrbf  = (const float*)d_in[10];
    const float* brbf  = (const float*)d_in[11];
    const float* W     = (const float*)d_in[12];
    const float* bias  = (const float*)d_in[13];
    unsigned short* ws = (unsigned short*)d_ws;
    unsigned char* wsb = (unsigned char*)d_ws;
    float* out = (float*)d_out;

    prestage_kernel<<<IDX_BLOCKS + TSD_BLOCKS + TSE_BLOCKS + TR_BLOCKS, 256, 0, stream>>>(
        Z, stepv, src, dst, equiv, rbf, dvec,
        emb, stept, eqt, Wrbf, W, bias, ws, wsb, out);
    edge_kernel<<<768, 256, 0, stream>>>(ws, wsb, brbf, out);
}